// Round 12
// baseline (382.367 us; speedup 1.0000x reference)
//
#include <hip/hip_runtime.h>
#include <stdint.h>

#define NEGV -1.0e9f
#define EPSV 1e-12f

typedef __attribute__((ext_vector_type(8))) short bf16x8;
typedef __attribute__((ext_vector_type(4))) float f32x4;

__device__ __forceinline__ unsigned int f2bf(float f) {
  unsigned int u = __builtin_bit_cast(unsigned int, f);
  u = u + 0x7FFFu + ((u >> 16) & 1u);   // round-to-nearest-even
  return u >> 16;
}

// RNE pack of two f32 -> packed bf16x2 in one VALU inst (same bits as f2bf pair;
// inputs are post-relu finite so NaN behavior is irrelevant).
__device__ __forceinline__ unsigned int cvt_pk_bf16(float lo, float hi) {
  unsigned int r;
  asm("v_cvt_pk_bf16_f32 %0, %1, %2" : "=v"(r) : "v"(lo), "v"(hi));
  return r;
}

// ---------------- k_prep: one launch, three independent jobs
__global__ __launch_bounds__(256) void k_prep(
    const float* __restrict__ state, const float* __restrict__ w1,
    const float* __restrict__ b1, const float* __restrict__ emb_w,
    const float* __restrict__ emb_b, const float* __restrict__ w2,
    float* __restrict__ W1e, float* __restrict__ sb,
    unsigned short* __restrict__ W2t) {
  const int blk = blockIdx.x;
  const int tid = threadIdx.x;
  if (blk < 4) {
    const int j = blk * 256 + tid;
    float a0 = 0.f, a1 = 0.f, a2 = 0.f, a3 = 0.f, a4 = 0.f;
    for (int e = 0; e < 256; ++e) {
      const float w = w1[(size_t)(512 + e) * 1024 + j];
      a0 += emb_w[0 * 256 + e] * w;
      a1 += emb_w[1 * 256 + e] * w;
      a2 += emb_w[2 * 256 + e] * w;
      a3 += emb_w[3 * 256 + e] * w;
      a4 += emb_w[4 * 256 + e] * w;
    }
    W1e[0 * 1024 + j] = a0;
    W1e[1 * 1024 + j] = a1;
    W1e[2 * 1024 + j] = a2;
    W1e[3 * 1024 + j] = a3;
    W1e[4 * 1024 + j] = a4;
  } else if (blk < 516) {
    const int blk2 = blk - 4;
    const int b = blk2 >> 2;
    const int j = (blk2 & 3) * 256 + tid;
    float acc = b1[j];
    for (int e = 0; e < 256; ++e)
      acc += emb_b[e] * w1[(size_t)(512 + e) * 1024 + j];
    const float* st = state + (size_t)b * 512;
    for (int s = 0; s < 512; ++s) acc += st[s] * w1[(size_t)s * 1024 + j];
    sb[(size_t)b * 1024 + j] = acc;
  } else {
    __shared__ float tile[64][65];
    const int blk2 = blk - 516;
    const int gn = blk2 & 15, gk = blk2 >> 4;
    const int c = tid & 63, w = tid >> 6;
#pragma unroll
    for (int i = 0; i < 16; ++i) {
      const int r = i * 4 + w;
      tile[r][c] = w2[(size_t)(gk * 64 + r) * 1024 + gn * 64 + c];
    }
    __syncthreads();
#pragma unroll
    for (int i = 0; i < 16; ++i) {
      const int r = i * 4 + w;
      W2t[(size_t)(gn * 64 + r) * 1024 + gk * 64 + c] = (unsigned short)f2bf(tile[c][r]);
    }
  }
}

// ---------------- k_h1: materialize H1 = relu(tf @ W1e + sb) as bf16 [65536][1024].
// 8 rows per thread (W1e regs amortized 8x); tf rows preloaded; coalesced 16B writes.
__global__ __launch_bounds__(256) void k_h1(
    const float* __restrict__ tf, const float* __restrict__ sbm,
    const float* __restrict__ W1em, unsigned short* __restrict__ H1) {
  const int tid = threadIdx.x;
  const int j0 = (tid & 127) << 3;
  const int r0 = (blockIdx.x * 2 + (tid >> 7)) * 8;   // 8 rows per thread
  const int b = r0 >> 9;
  float ptf[8][5];
#pragma unroll
  for (int r = 0; r < 8; ++r) {
    const float* f = tf + (size_t)(r0 + r) * 5;
#pragma unroll
    for (int i = 0; i < 5; ++i) ptf[r][i] = f[i];
  }
  const float* sbp = sbm + (size_t)b * 1024 + j0;
  const float4 sa = *(const float4*)(sbp);
  const float4 sbv = *(const float4*)(sbp + 4);
  float4 wa[5], wb[5];
#pragma unroll
  for (int i = 0; i < 5; ++i) {
    wa[i] = *(const float4*)(W1em + i * 1024 + j0);
    wb[i] = *(const float4*)(W1em + i * 1024 + j0 + 4);
  }
#pragma unroll
  for (int r = 0; r < 8; ++r) {
    const float f0 = ptf[r][0], f1 = ptf[r][1], f2 = ptf[r][2],
                f3 = ptf[r][3], f4 = ptf[r][4];
    float h0 = fmaf(f4, wa[4].x, fmaf(f3, wa[3].x, fmaf(f2, wa[2].x, fmaf(f1, wa[1].x, fmaf(f0, wa[0].x, sa.x)))));
    float h1 = fmaf(f4, wa[4].y, fmaf(f3, wa[3].y, fmaf(f2, wa[2].y, fmaf(f1, wa[1].y, fmaf(f0, wa[0].y, sa.y)))));
    float h2 = fmaf(f4, wa[4].z, fmaf(f3, wa[3].z, fmaf(f2, wa[2].z, fmaf(f1, wa[1].z, fmaf(f0, wa[0].z, sa.z)))));
    float h3 = fmaf(f4, wa[4].w, fmaf(f3, wa[3].w, fmaf(f2, wa[2].w, fmaf(f1, wa[1].w, fmaf(f0, wa[0].w, sa.w)))));
    float h4 = fmaf(f4, wb[4].x, fmaf(f3, wb[3].x, fmaf(f2, wb[2].x, fmaf(f1, wb[1].x, fmaf(f0, wb[0].x, sbv.x)))));
    float h5 = fmaf(f4, wb[4].y, fmaf(f3, wb[3].y, fmaf(f2, wb[2].y, fmaf(f1, wb[1].y, fmaf(f0, wb[0].y, sbv.y)))));
    float h6 = fmaf(f4, wb[4].z, fmaf(f3, wb[3].z, fmaf(f2, wb[2].z, fmaf(f1, wb[1].z, fmaf(f0, wb[0].z, sbv.z)))));
    float h7 = fmaf(f4, wb[4].w, fmaf(f3, wb[3].w, fmaf(f2, wb[2].w, fmaf(f1, wb[1].w, fmaf(f0, wb[0].w, sbv.w)))));
    h0 = fmaxf(h0, 0.f); h1 = fmaxf(h1, 0.f); h2 = fmaxf(h2, 0.f); h3 = fmaxf(h3, 0.f);
    h4 = fmaxf(h4, 0.f); h5 = fmaxf(h5, 0.f); h6 = fmaxf(h6, 0.f); h7 = fmaxf(h7, 0.f);
    uint4 pk;
    pk.x = cvt_pk_bf16(h0, h1);
    pk.y = cvt_pk_bf16(h2, h3);
    pk.z = cvt_pk_bf16(h4, h5);
    pk.w = cvt_pk_bf16(h6, h7);
    *(uint4*)&H1[(size_t)(r0 + r) * 1024 + j0] = pk;
  }
}

// ---------------- k_gemm2: 8-wave 256x256 GEMM (H1 @ W2t), A DIRECT FROM GLOBAL.
// R22: five schedules (R7-R10) all hit the same wall: per tile, LDS-read pipe
// (24 b128/wave = ~2300 cyc/CU) + MFMA (2483 cyc/SIMD) execute additively.
// This round REDUCES the LDS traffic instead of rescheduling it: A-fragments
// are lane-regular in GLOBAL memory (lane = row base+lm, chunk lg -> 16 rows
// x 64B contiguous per m-frag, perfectly line-coalesced), so A loads go
// global->VGPR directly. B (2MB, shared by all blocks) stays LDS-staged.
//   - LDS reads: 24 -> 8 b128/wave/tile (~770 cyc); LDS 128KB -> 64KB.
//   - A comes from L2/L3 (H1 is warm; 4 by-blocks/XCD share each panel;
//     4 waves/block share lines within a phase window).
//   - A prefetch one phase ahead; p2 also issues next-tile p0 frags. ALL
//     waits are compiler-emitted counted vmcnt (queue: p1 sees vmcnt(8),
//     p2 vmcnt(10), p3 vmcnt(4) - the p3 wait retires all B staging before
//     the tile-end barrier, so B double-buffer safety needs NO manual waits).
// Sentinels: LDS_Block_Size 65536, VGPR<=128, WRITE_SIZE 4096KB, conflicts 0.
__global__ __launch_bounds__(512, 2) void k_gemm2(
    const unsigned short* __restrict__ H1, const unsigned short* __restrict__ W2t,
    const float* __restrict__ b2, const float* __restrict__ w3,
    float* __restrict__ partial) {
  __shared__ unsigned short Bs[2][16384];   // [buf][256 cols][64 k] swizzled

  const int bid = blockIdx.x;
  const int swz = (bid & 7) * 128 + (bid >> 3);   // XCD swizzle (1024 % 8 == 0)
  const int bx = swz >> 2, by = swz & 3;
  const int row0 = bx << 8, col0 = by << 8;

  const int tid = threadIdx.x, lane = tid & 63, wid = tid >> 6;

  // ---- B staging: 4 loads/thread/tile, 2 per STAGEB2 call.
  // load q covers cols q*64..q*64+63: col = q*64 + wid*8 + (lane>>3), 8 chunks.
  const int bcol = (wid << 3) + (lane >> 3);
  const int bscol = (((lane & 7) ^ ((lane >> 3) & 7)) << 3);  // pre-swizzled src chunk

#define STAGEB2(kt, g)                                                        \
    _Pragma("unroll")                                                         \
    for (int q = 2 * (g); q < 2 * (g) + 2; ++q) {                             \
      __builtin_amdgcn_global_load_lds(                                       \
          (const __attribute__((address_space(1))) void*)(                    \
              W2t + (size_t)(col0 + q * 64 + bcol) * 1024 + (kt) * 64 + bscol), \
          (__attribute__((address_space(3))) void*)(                          \
              Bs[(kt) & 1] + (q * 64 + (wid << 3)) * 64), 16, 0, 0);          \
    }

  // ---- consumer constants
  const int wr = wid >> 2, wc = wid & 3;
  const int lm = lane & 15, lg = lane >> 4;
  const int boff = (wc * 64 + lm) * 64;         // + n*1024 + s{0,1}
  const int s0 = ((lg ^ (lm & 7)) << 3);        // k16 = lg
  const int s1 = (((4 + lg) ^ (lm & 7)) << 3);  // k16 = 4+lg
  // A direct-from-global per-thread base: row = row0 + wr*128 + lm, chunk lg.
  // frag(m, half) of tile t at aptr + m*16384 + t*64 + half*32 (elements).
  const unsigned short* aptr = H1 + (size_t)(row0 + wr * 128 + lm) * 1024 + lg * 8;

  f32x4 acc[8][4];
#pragma unroll
  for (int m = 0; m < 8; ++m)
#pragma unroll
    for (int n = 0; n < 4; ++n) acc[m][n] = (f32x4){0.f, 0.f, 0.f, 0.f};

  // ---- prologue: stage B tile 0; prefetch A frags for (t0, p0); full drain.
  STAGEB2(0, 0);
  STAGEB2(0, 1);
  bf16x8 ANf[4], A1f[4], A0f[4];
  ANf[0] = *(const bf16x8*)(aptr + 0);
  ANf[1] = *(const bf16x8*)(aptr + 32);
  ANf[2] = *(const bf16x8*)(aptr + 16384);
  ANf[3] = *(const bf16x8*)(aptr + 16384 + 32);
  asm volatile("s_waitcnt vmcnt(0)" ::: "memory");
  __builtin_amdgcn_s_barrier();

#define MFMA16(mp, F)                                                         \
    _Pragma("unroll")                                                         \
    for (int n = 0; n < 4; ++n)                                               \
      acc[2 * (mp)][n] = __builtin_amdgcn_mfma_f32_16x16x32_bf16(F[0], bk0[n], acc[2 * (mp)][n], 0, 0, 0); \
    _Pragma("unroll")                                                         \
    for (int n = 0; n < 4; ++n)                                               \
      acc[2 * (mp) + 1][n] = __builtin_amdgcn_mfma_f32_16x16x32_bf16(F[2], bk0[n], acc[2 * (mp) + 1][n], 0, 0, 0); \
    _Pragma("unroll")                                                         \
    for (int n = 0; n < 4; ++n)                                               \
      acc[2 * (mp)][n] = __builtin_amdgcn_mfma_f32_16x16x32_bf16(F[1], bk1[n], acc[2 * (mp)][n], 0, 0, 0); \
    _Pragma("unroll")                                                         \
    for (int n = 0; n < 4; ++n)                                               \
      acc[2 * (mp) + 1][n] = __builtin_amdgcn_mfma_f32_16x16x32_bf16(F[3], bk1[n], acc[2 * (mp) + 1][n], 0, 0, 0);

#pragma unroll 1
  for (int t = 0; t < 16; ++t) {
    const unsigned short* Bd = Bs[t & 1];
    bf16x8 bk0[4], bk1[4];
#pragma unroll
    for (int n = 0; n < 4; ++n) {
      bk0[n] = *(const bf16x8*)(Bd + boff + n * 1024 + s0);
      bk1[n] = *(const bf16x8*)(Bd + boff + n * 1024 + s1);
    }
    // ---- p0: consume ANf (m0,1); issue A1f (m2,3); stage B half 0
    A1f[0] = *(const bf16x8*)(aptr + 2 * 16384 + t * 64);
    A1f[1] = *(const bf16x8*)(aptr + 2 * 16384 + t * 64 + 32);
    A1f[2] = *(const bf16x8*)(aptr + 3 * 16384 + t * 64);
    A1f[3] = *(const bf16x8*)(aptr + 3 * 16384 + t * 64 + 32);
    if (t < 15) STAGEB2(t + 1, 0);
    __builtin_amdgcn_s_setprio(1);
    MFMA16(0, ANf);
    __builtin_amdgcn_s_setprio(0);
    __builtin_amdgcn_s_barrier();
    // ---- p1: consume A1f (m2,3); issue A0f (m4,5); stage B half 1
    A0f[0] = *(const bf16x8*)(aptr + 4 * 16384 + t * 64);
    A0f[1] = *(const bf16x8*)(aptr + 4 * 16384 + t * 64 + 32);
    A0f[2] = *(const bf16x8*)(aptr + 5 * 16384 + t * 64);
    A0f[3] = *(const bf16x8*)(aptr + 5 * 16384 + t * 64 + 32);
    if (t < 15) STAGEB2(t + 1, 1);
    __builtin_amdgcn_s_setprio(1);
    MFMA16(1, A1f);
    __builtin_amdgcn_s_setprio(0);
    __builtin_amdgcn_s_barrier();
    // ---- p2: consume A0f (m4,5); issue A1f (m6,7) THEN ANf (t+1, m0,1)
    A1f[0] = *(const bf16x8*)(aptr + 6 * 16384 + t * 64);
    A1f[1] = *(const bf16x8*)(aptr + 6 * 16384 + t * 64 + 32);
    A1f[2] = *(const bf16x8*)(aptr + 7 * 16384 + t * 64);
    A1f[3] = *(const bf16x8*)(aptr + 7 * 16384 + t * 64 + 32);
    if (t < 15) {
      ANf[0] = *(const bf16x8*)(aptr + (t + 1) * 64);
      ANf[1] = *(const bf16x8*)(aptr + (t + 1) * 64 + 32);
      ANf[2] = *(const bf16x8*)(aptr + 16384 + (t + 1) * 64);
      ANf[3] = *(const bf16x8*)(aptr + 16384 + (t + 1) * 64 + 32);
    }
    __builtin_amdgcn_s_setprio(1);
    MFMA16(2, A0f);
    __builtin_amdgcn_s_setprio(0);
    __builtin_amdgcn_s_barrier();
    // ---- p3: consume A1f (m6,7). Compiler's pre-MFMA wait (vmcnt(4):
    // only ANf newer in queue) retires ALL this tile's B staging before the
    // tile-end barrier -> buffer handoff safe with zero manual waits.
    __builtin_amdgcn_s_setprio(1);
    MFMA16(3, A1f);
    __builtin_amdgcn_s_setprio(0);
    __builtin_amdgcn_s_barrier();
  }
#undef MFMA16
#undef STAGEB2

  // ---- epilogue: partial[row][by*4+wc] = sum_cols relu(acc + b2[col]) * w3[col]
  float b2v[4], w3v[4];
#pragma unroll
  for (int n = 0; n < 4; ++n) {
    const int col = col0 + wc * 64 + n * 16 + lm;
    b2v[n] = b2[col];
    w3v[n] = w3[col];
  }
#pragma unroll
  for (int m = 0; m < 8; ++m) {
#pragma unroll
    for (int r = 0; r < 4; ++r) {
      float v = 0.f;
#pragma unroll
      for (int n = 0; n < 4; ++n) {
        float h = acc[m][n][r] + b2v[n];
        h = fmaxf(h, 0.f);
        v += h * w3v[n];
      }
      v += __shfl_xor(v, 1, 16);
      v += __shfl_xor(v, 2, 16);
      v += __shfl_xor(v, 4, 16);
      v += __shfl_xor(v, 8, 16);
      if (lm == 0)
        partial[(size_t)(row0 + wr * 128 + m * 16 + lg * 4 + r) * 16 + by * 4 + wc] = v;
    }
  }
}

// ---------------- k_softmax: fused utils-reduction + nested-logit softmax
// 512 threads, 1 task/thread; cross-wave via LDS.
__global__ __launch_bounds__(512) void k_softmax(
    const float* __restrict__ partial, const float* __restrict__ b3,
    const int* __restrict__ nids, const int* __restrict__ mask,
    const float* __restrict__ etas, float* __restrict__ utils_out,
    float* __restrict__ p_task, float* __restrict__ p_nest) {
  const int b = blockIdx.x, tid = threadIdx.x;
  const int lane = tid & 63, wv = tid >> 6;
  __shared__ float smax[8][4];
  __shared__ int scnt[8][4];
  __shared__ float ssum[8][4];
  __shared__ float sred[8];
  __shared__ int sredi[8];

  const size_t base = (size_t)b * 512;
  const float b3v = b3[0];
  const size_t row = base + tid;
  const float4* p = (const float4*)(partial + row * 16);
  const float4 pa = p[0], pb = p[1], pc = p[2], pd = p[3];
  const float uraw = b3v + pa.x + pa.y + pa.z + pa.w + pb.x + pb.y + pb.z + pb.w +
                     pc.x + pc.y + pc.z + pc.w + pd.x + pd.y + pd.z + pd.w;
  const int n0 = nids[row];
  const bool m0 = mask[row] != 0;
  const float u0 = m0 ? uraw : NEGV;
  utils_out[row] = u0;
  const float eta[4] = {etas[0], etas[1], etas[2], etas[3]};

  float lmax[4]; int lcnt[4];
#pragma unroll
  for (int m = 0; m < 4; ++m) {
    const bool e0 = m0 && (n0 == m);
    lmax[m] = e0 ? u0 : -INFINITY;
    lcnt[m] = (int)e0;
  }
#pragma unroll
  for (int m = 0; m < 4; ++m)
#pragma unroll
    for (int off = 32; off >= 1; off >>= 1) {
      lmax[m] = fmaxf(lmax[m], __shfl_xor(lmax[m], off));
      lcnt[m] += __shfl_xor(lcnt[m], off);
    }
  if (lane == 0) {
#pragma unroll
    for (int m = 0; m < 4; ++m) { smax[wv][m] = lmax[m]; scnt[wv][m] = lcnt[m]; }
  }
  __syncthreads();
  float mval[4]; bool ne[4];
#pragma unroll
  for (int m = 0; m < 4; ++m) {
    float mx = smax[0][m];
    int c = scnt[0][m];
#pragma unroll
    for (int w = 1; w < 8; ++w) { mx = fmaxf(mx, smax[w][m]); c += scnt[w][m]; }
    ne[m] = c > 0;
    mval[m] = ne[m] ? mx : 0.f;
  }
  float lsum[4];
#pragma unroll
  for (int m = 0; m < 4; ++m)
    lsum[m] = (m0 && n0 == m) ? expf((u0 - mval[m]) / eta[m]) : 0.f;
#pragma unroll
  for (int m = 0; m < 4; ++m)
#pragma unroll
    for (int off = 32; off >= 1; off >>= 1) lsum[m] += __shfl_xor(lsum[m], off);
  if (lane == 0) {
#pragma unroll
    for (int m = 0; m < 4; ++m) ssum[wv][m] = lsum[m];
  }
  __syncthreads();
  float sums[4], U[4];
#pragma unroll
  for (int m = 0; m < 4; ++m) {
    float s = ssum[0][m];
#pragma unroll
    for (int w = 1; w < 8; ++w) s += ssum[w][m];
    sums[m] = fmaxf(s, EPSV);
    U[m] = ne[m] ? (mval[m] + eta[m] * logf(sums[m])) : NEGV;
  }
  const float mU = fmaxf(fmaxf(U[0], U[1]), fmaxf(U[2], U[3]));
  float pe[4], pes = 0.f;
#pragma unroll
  for (int m = 0; m < 4; ++m) { pe[m] = expf(U[m] - mU); pes += pe[m]; }
  float pn[4];
#pragma unroll
  for (int m = 0; m < 4; ++m) pn[m] = pe[m] / pes;
  if (tid == 0) {
#pragma unroll
    for (int m = 0; m < 4; ++m) p_nest[(size_t)b * 4 + m] = pn[m];
  }
  const bool valid = m0 && n0 >= 0 && n0 < 4;
  float mt = 0.f, st = 1.f, pnt = 0.f, et = 1.f;
#pragma unroll
  for (int m = 0; m < 4; ++m)
    if (n0 == m) { mt = mval[m]; st = sums[m]; pnt = pn[m]; et = eta[m]; }
  float pt = valid ? pnt * expf((u0 - mt) / et) / st : 0.f;

  float lp = pt;
  int lmk = (int)m0;
#pragma unroll
  for (int off = 32; off >= 1; off >>= 1) {
    lp += __shfl_xor(lp, off);
    lmk += __shfl_xor(lmk, off);
  }
  if (lane == 0) { sred[wv] = lp; sredi[wv] = lmk; }
  __syncthreads();
  float sumpt = sred[0];
  int nmask = sredi[0];
#pragma unroll
  for (int w = 1; w < 8; ++w) { sumpt += sred[w]; nmask += sredi[w]; }
  const bool fallback = (nmask > 0) && (sumpt <= EPSV);
  if (fallback) {
    const float uni = 1.f / (float)(nmask > 0 ? nmask : 1);
    pt = m0 ? uni : pt;
  }
  p_task[row] = pt;
}

extern "C" void kernel_launch(void* const* d_in, const int* in_sizes, int n_in,
                              void* d_out, int out_size, void* d_ws, size_t ws_size,
                              hipStream_t stream) {
  const float* state = (const float*)d_in[0];
  const float* tf = (const float*)d_in[1];
  const int* nids = (const int*)d_in[2];
  const int* mask = (const int*)d_in[3];
  const float* emb_w = (const float*)d_in[4];
  const float* emb_b = (const float*)d_in[5];
  const float* w1 = (const float*)d_in[6];
  const float* b1 = (const float*)d_in[7];
  const float* w2 = (const float*)d_in[8];
  const float* b2 = (const float*)d_in[9];
  const float* w3 = (const float*)d_in[10];
  const float* b3 = (const float*)d_in[11];
  const float* etas = (const float*)d_in[12];

  float* out = (float*)d_out;
  float* utils_out = out;            // 65536
  float* p_task = out + 65536;       // 65536
  float* p_nest = out + 131072;      // 512

  char* ws = (char*)d_ws;
  unsigned short* W2t = (unsigned short*)ws; ws += 1024ull * 1024 * 2;    // 2 MB
  float* partial = (float*)ws;               ws += 65536ull * 16 * 4;     // 4 MB
  float* W1e = (float*)ws;                   ws += 5 * 1024 * 4;
  float* sb = (float*)ws;                    ws += 128 * 1024 * 4;
  unsigned short* H1 = (unsigned short*)ws;  ws += 65536ull * 1024 * 2;   // 128 MB

  k_prep<<<772, 256, 0, stream>>>(state, w1, b1, emb_w, emb_b, w2, W1e, sb, W2t);
  k_h1<<<4096, 256, 0, stream>>>(tf, sb, W1e, H1);
  k_gemm2<<<1024, 512, 0, stream>>>(H1, W2t, b2, w3, partial);
  k_softmax<<<128, 512, 0, stream>>>(partial, b3, nids, mask, etas,
                                     utils_out, p_task, p_nest);
}